// Round 1
// baseline (256.598 us; speedup 1.0000x reference)
//
#include <hip/hip_runtime.h>

// Blocks SNN forward: T=1024, TB=8, B=32, N=1024.
// One thread per (b,n) chain; all 128 time-blocks sequential per thread.
// State carried in f64 to match the harness's float64 numpy reference on
// every heaviside decision (fp32 reassociation would flip ~1e-7 margins).

constexpr int T_LEN = 1024;
constexpr int TB    = 8;
constexpr int NBLK  = T_LEN / TB;   // 128
constexpr int BATCH = 32;
constexpr int NOUT  = 1024;
constexpr int BN    = BATCH * NOUT; // 32768 chains
constexpr int PF    = 4;            // prefetch depth in blocks (32 loads in flight)

__global__ __launch_bounds__(64)
void snn_blocks_kernel(const float* __restrict__ x,
                       const float* __restrict__ beta_raw,
                       const float* __restrict__ p_raw,
                       const float* __restrict__ b_raw,
                       float* __restrict__ out)
{
    const int gid = blockIdx.x * 64 + threadIdx.x;  // = b*NOUT + n
    const int n   = gid & (NOUT - 1);

    // clamped properties (f64)
    double beta = (double)beta_raw[n];
    beta = beta < 0.001 ? 0.001 : (beta > 0.999 ? 0.999 : beta);
    double p = fabs((double)p_raw[n]);
    p = p > 0.999 ? 0.999 : p;
    double bb = fabs((double)b_raw[n]);
    bb = bb < 0.001 ? 0.001 : (bb > 1.0 ? 1.0 : bb);
    const double inv_p = 1.0 / p;

    double ppow[9];                 // p^0 .. p^8
    ppow[0] = 1.0;
#pragma unroll
    for (int i = 1; i <= 8; ++i) ppow[i] = ppow[i - 1] * p;

    double bbp[8];                  // bb * p^(t+1)
#pragma unroll
    for (int t = 0; t < 8; ++t) bbp[t] = bb * ppow[t + 1];

    // carry state
    double m = 0.0;                 // int_mem / running membrane
    double a = 0.0;                 // a_kernel scalar (a_k[t] = p^(t+1)*a)
    int zprev[8];
#pragma unroll
    for (int t = 0; t < 8; ++t) zprev[t] = 0;

    const float* xg = x + gid;
    float*       og = out + gid;

    // register prefetch buffer: PF blocks x 8 timesteps
    float xb[PF][8];
#pragma unroll
    for (int k = 0; k < PF; ++k) {
#pragma unroll
        for (int t = 0; t < 8; ++t)
            xb[k][t] = xg[(ptrdiff_t)(k * TB + t) * BN];
    }

#pragma unroll 4   // PF=4 divides 128 -> slot is compile-time constant
    for (int blk = 0; blk < NBLK; ++blk) {
        const int slot = blk & (PF - 1);
        float cur[8];
#pragma unroll
        for (int t = 0; t < 8; ++t) cur[t] = xb[slot][t];

        const int pfb = blk + PF;
        if (pfb < NBLK) {
#pragma unroll
            for (int t = 0; t < 8; ++t)
                xb[slot][t] = xg[(ptrdiff_t)(pfb * TB + t) * BN];
        }

        // block-level scalars from previous block's z / spikes
        int maskf = 0;      // any prev spike (z==1)
        int decay = 0;      // count(z > 1)
        double ssum = 0.0;  // sum_t p^(t+1) * spike[t]
#pragma unroll
        for (int t = 0; t < 8; ++t) {
            maskf |= (zprev[t] == 1);
            decay += (zprev[t] > 1) ? 1 : 0;
            ssum  += (zprev[t] == 1) ? ppow[t + 1] : 0.0;
        }

        const double a_at = a * ssum + inv_p;
        double pd = 1.0;                        // p^decay, decay in [0,8]
        pd *= (decay & 1) ? p       : 1.0;
        pd *= (decay & 2) ? ppow[2] : 1.0;
        pd *= (decay & 4) ? ppow[4] : 1.0;
        pd *= (decay & 8) ? ppow[8] : 1.0;
        const double new_a = a_at * pd;

        if (maskf) { a = new_a;      m = 0.0; } // v_init = 0
        else       { a = ppow[8] * a;          } // v_init = int_mem (m kept)

        int c = 0, zc = 0;
        float* o = og + (ptrdiff_t)blk * TB * BN;
#pragma unroll
        for (int t = 0; t < 8; ++t) {
            double xv = (double)cur[t];
            if (maskf && zprev[t] == 0) xv = 0.0;   // refractory input mask
            m = beta * m + xv;                       // causal decayed sum
            const double vth = 1.0 + bbp[t] * a;     // 1 + bb * p^(t+1) * a
            const int f = (m - vth > 0.0) ? 1 : 0;   // heaviside, strict >
            c  += f;                                 // cumsum(faulty)
            zc += c;                                 // z_new = cumsum(cumsum)
            zprev[t] = zc;
            o[(ptrdiff_t)t * BN] = (zc == 1) ? 1.0f : 0.0f;
        }
    }
}

extern "C" void kernel_launch(void* const* d_in, const int* in_sizes, int n_in,
                              void* d_out, int out_size, void* d_ws, size_t ws_size,
                              hipStream_t stream) {
    const float* x        = (const float*)d_in[0];
    const float* beta_raw = (const float*)d_in[1];
    const float* p_raw    = (const float*)d_in[2];
    const float* b_raw    = (const float*)d_in[3];
    float* out            = (float*)d_out;

    dim3 grid(BN / 64);   // 512 workgroups of 1 wave -> spread over 256 CUs
    dim3 block(64);
    snn_blocks_kernel<<<grid, block, 0, stream>>>(x, beta_raw, p_raw, b_raw, out);
}

// Round 2
// 248.572 us; speedup vs baseline: 1.0323x; 1.0323x over previous
//
#include <hip/hip_runtime.h>

// Blocks SNN forward: T=1024, TB=8, B=32, N=1024.
// One thread per (b,n) chain; 128 sequential time-blocks per thread.
// State in f64 to match the harness's float64 numpy reference on every
// heaviside decision (fp32 reassociation flips ~1e-7 margins).
//
// R2: __launch_bounds__(64,1) to unlock VGPRs (R1 compiled to 56 VGPRs and
// serialized the prefetch -> latency-bound at 102us). PF=8 register prefetch
// (64 outstanding 4B loads/wave ~= 16KB in flight) + nontemporal stores so
// the 134MB output stream doesn't evict x from L2/L3.

constexpr int T_LEN = 1024;
constexpr int TB    = 8;
constexpr int NBLK  = T_LEN / TB;   // 128
constexpr int BATCH = 32;
constexpr int NOUT  = 1024;
constexpr int BN    = BATCH * NOUT; // 32768 chains
constexpr int PF    = 8;            // prefetch depth in blocks (64 loads in flight)

__global__ __launch_bounds__(64, 1)
void snn_blocks_kernel(const float* __restrict__ x,
                       const float* __restrict__ beta_raw,
                       const float* __restrict__ p_raw,
                       const float* __restrict__ b_raw,
                       float* __restrict__ out)
{
    const int gid = blockIdx.x * 64 + threadIdx.x;  // = b*NOUT + n
    const int n   = gid & (NOUT - 1);

    // clamped properties (f64)
    double beta = (double)beta_raw[n];
    beta = beta < 0.001 ? 0.001 : (beta > 0.999 ? 0.999 : beta);
    double p = fabs((double)p_raw[n]);
    p = p > 0.999 ? 0.999 : p;
    double bb = fabs((double)b_raw[n]);
    bb = bb < 0.001 ? 0.001 : (bb > 1.0 ? 1.0 : bb);
    const double inv_p = 1.0 / p;

    double ppow[9];                 // p^0 .. p^8
    ppow[0] = 1.0;
#pragma unroll
    for (int i = 1; i <= 8; ++i) ppow[i] = ppow[i - 1] * p;

    double bbp[8];                  // bb * p^(t+1)
#pragma unroll
    for (int t = 0; t < 8; ++t) bbp[t] = bb * ppow[t + 1];

    // carry state
    double m = 0.0;                 // int_mem / running membrane
    double a = 0.0;                 // a_kernel scalar (a_k[t] = p^(t+1)*a)
    int zprev[8];
#pragma unroll
    for (int t = 0; t < 8; ++t) zprev[t] = 0;

    const float* xg = x + gid;
    float*       og = out + gid;

    // register prefetch buffer: PF blocks x 8 timesteps
    float xb[PF][8];
#pragma unroll
    for (int k = 0; k < PF; ++k) {
#pragma unroll
        for (int t = 0; t < 8; ++t)
            xb[k][t] = xg[(ptrdiff_t)(k * TB + t) * BN];
    }

#pragma unroll 8   // PF=8 divides 128 -> slot is compile-time constant
    for (int blk = 0; blk < NBLK; ++blk) {
        const int slot = blk & (PF - 1);
        float cur[8];
#pragma unroll
        for (int t = 0; t < 8; ++t) cur[t] = xb[slot][t];

        const int pfb = blk + PF;
        if (pfb < NBLK) {
#pragma unroll
            for (int t = 0; t < 8; ++t)
                xb[slot][t] = xg[(ptrdiff_t)(pfb * TB + t) * BN];
        }

        // block-level scalars from previous block's z / spikes
        int maskf = 0;      // any prev spike (z==1)
        int decay = 0;      // count(z > 1)
        double ssum = 0.0;  // sum_t p^(t+1) * spike[t]
#pragma unroll
        for (int t = 0; t < 8; ++t) {
            maskf |= (zprev[t] == 1);
            decay += (zprev[t] > 1) ? 1 : 0;
            ssum  += (zprev[t] == 1) ? ppow[t + 1] : 0.0;
        }

        const double a_at = a * ssum + inv_p;
        double pd = 1.0;                        // p^decay, decay in [0,8]
        pd *= (decay & 1) ? p       : 1.0;
        pd *= (decay & 2) ? ppow[2] : 1.0;
        pd *= (decay & 4) ? ppow[4] : 1.0;
        pd *= (decay & 8) ? ppow[8] : 1.0;
        const double new_a = a_at * pd;

        if (maskf) { a = new_a;      m = 0.0; } // v_init = 0
        else       { a = ppow[8] * a;          } // v_init = int_mem (m kept)

        int c = 0, zc = 0;
        float* o = og + (ptrdiff_t)blk * TB * BN;
#pragma unroll
        for (int t = 0; t < 8; ++t) {
            double xv = (double)cur[t];
            if (maskf && zprev[t] == 0) xv = 0.0;   // refractory input mask
            m = beta * m + xv;                       // causal decayed sum
            const double vth = 1.0 + bbp[t] * a;     // 1 + bb * p^(t+1) * a
            const int f = (m - vth > 0.0) ? 1 : 0;   // heaviside, strict >
            c  += f;                                 // cumsum(faulty)
            zc += c;                                 // z_new = cumsum(cumsum)
            zprev[t] = zc;
            __builtin_nontemporal_store((zc == 1) ? 1.0f : 0.0f,
                                        o + (ptrdiff_t)t * BN);
        }
    }
}

extern "C" void kernel_launch(void* const* d_in, const int* in_sizes, int n_in,
                              void* d_out, int out_size, void* d_ws, size_t ws_size,
                              hipStream_t stream) {
    const float* x        = (const float*)d_in[0];
    const float* beta_raw = (const float*)d_in[1];
    const float* p_raw    = (const float*)d_in[2];
    const float* b_raw    = (const float*)d_in[3];
    float* out            = (float*)d_out;

    dim3 grid(BN / 64);   // 512 workgroups of 1 wave -> spread over 256 CUs
    dim3 block(64);
    snn_blocks_kernel<<<grid, block, 0, stream>>>(x, beta_raw, p_raw, b_raw, out);
}

// Round 3
// 246.525 us; speedup vs baseline: 1.0409x; 1.0083x over previous
//
#include <hip/hip_runtime.h>

// Blocks SNN forward: T=1024, TB=8, B=32, N=1024.
// One thread per (b,n) chain; 128 sequential time-blocks per thread.
// State in f64 to match the harness's float64 numpy reference on every
// heaviside decision (fp32 reassociation flips ~1e-7 margins).
//
// R3: async global->LDS pipeline. R2's register prefetch was sunk by the
// compiler (VGPR=72 proves the 64-float buffer never existed) -> exposed
// load latency at 2 waves/CU. global_load_lds cannot be sunk; 5-slot LDS
// ring, PF=4 blocks ahead, manual s_waitcnt vmcnt(N) gating (ramp
// 24/32/40 -> 48 steady -> 16 tail). Stores nontemporal, never waited on.

constexpr int T_LEN = 1024;
constexpr int TB    = 8;
constexpr int NBLK  = T_LEN / TB;   // 128
constexpr int BATCH = 32;
constexpr int NOUT  = 1024;
constexpr int BN    = BATCH * NOUT; // 32768 chains
constexpr int PF    = 4;            // prefetch depth (blocks)
constexpr int SLOTS = 5;            // LDS ring slots (> PF)

#define WAITVM(N) asm volatile("s_waitcnt vmcnt(" #N ")" ::: "memory")

typedef const __attribute__((address_space(1))) void* gptr_t;
typedef __attribute__((address_space(3))) void*       sptr_t;

__global__ __launch_bounds__(64, 1)
void snn_blocks_kernel(const float* __restrict__ x,
                       const float* __restrict__ beta_raw,
                       const float* __restrict__ p_raw,
                       const float* __restrict__ b_raw,
                       float* __restrict__ out)
{
    __shared__ float lds[SLOTS][TB][64];

    const int lane = threadIdx.x;
    const int gid  = blockIdx.x * 64 + lane;    // = b*NOUT + n
    const int n    = gid & (NOUT - 1);

    // clamped properties (f64)
    double beta = (double)beta_raw[n];
    beta = beta < 0.001 ? 0.001 : (beta > 0.999 ? 0.999 : beta);
    double p = fabs((double)p_raw[n]);
    p = p > 0.999 ? 0.999 : p;
    double bb = fabs((double)b_raw[n]);
    bb = bb < 0.001 ? 0.001 : (bb > 1.0 ? 1.0 : bb);
    const double inv_p = 1.0 / p;

    double ppow[9];                 // p^0 .. p^8
    ppow[0] = 1.0;
#pragma unroll
    for (int i = 1; i <= 8; ++i) ppow[i] = ppow[i - 1] * p;

    double bbp[8];                  // bb * p^(t+1)
#pragma unroll
    for (int t = 0; t < 8; ++t) bbp[t] = bb * ppow[t + 1];

    // carry state
    double m = 0.0;                 // running membrane / int_mem
    double a = 0.0;                 // a_kernel scalar (a_k[t] = p^(t+1)*a)
    int    maskf = 0;               // any spike (z==1) in prev block
    int    decay = 0;               // count(z>1) in prev block
    double ssum  = 0.0;             // sum_t p^(t+1)*spike[t] of prev block
    int    zzero = 0xFF;            // bit t set if prev z[t]==0

    const float* xg = x + gid;
    float*       og = out + gid;

    // preamble: stage blocks 0..PF-1 into slots 0..PF-1
#pragma unroll
    for (int k = 0; k < PF; ++k) {
#pragma unroll
        for (int t = 0; t < TB; ++t) {
            __builtin_amdgcn_global_load_lds(
                (gptr_t)(xg + (ptrdiff_t)(k * TB + t) * BN),
                (sptr_t)&lds[k][t][0], 4, 0, 0);
        }
    }

    int rs = 0;            // read slot
    int ws = PF % SLOTS;   // write slot for block blk+PF

    auto body = [&](int blk) {
        // consume block blk from lds[rs] (caller has done the vmcnt gate)
        float cur[8];
#pragma unroll
        for (int t = 0; t < 8; ++t) cur[t] = lds[rs][t][lane];

        // block header from previous block's stats
        const double a_at = a * ssum + inv_p;
        double pd = 1.0;                        // p^decay, decay in [0,8]
        pd *= (decay & 1) ? p       : 1.0;
        pd *= (decay & 2) ? ppow[2] : 1.0;
        pd *= (decay & 4) ? ppow[4] : 1.0;
        pd *= (decay & 8) ? ppow[8] : 1.0;
        const double new_a = a_at * pd;

        if (maskf) { a = new_a;     m = 0.0; }  // v_init = 0
        else       { a = ppow[8] * a;        }  // keep int_mem

        int nmaskf = 0, ndecay = 0, nzzero = 0;
        double nssum = 0.0;
        int c = 0, zc = 0;
        float* o = og + (ptrdiff_t)blk * TB * BN;
#pragma unroll
        for (int t = 0; t < 8; ++t) {
            double xv = (double)cur[t];
            if (maskf && ((zzero >> t) & 1)) xv = 0.0;  // refractory mask
            m = beta * m + xv;                           // causal decayed sum
            const double vth = 1.0 + bbp[t] * a;         // 1 + bb*p^(t+1)*a
            const int f = (m - vth > 0.0) ? 1 : 0;       // heaviside (strict >)
            c  += f;                                     // cumsum(faulty)
            zc += c;                                     // double cumsum
            nmaskf |= (zc == 1);
            ndecay += (zc > 1) ? 1 : 0;
            nssum  += (zc == 1) ? ppow[t + 1] : 0.0;
            nzzero |= (zc == 0) ? (1 << t) : 0;
            __builtin_nontemporal_store((zc == 1) ? 1.0f : 0.0f,
                                        o + (ptrdiff_t)t * BN);
        }
        maskf = nmaskf; decay = ndecay; ssum = nssum; zzero = nzzero;

        // prefetch block blk+PF into slot ws
        const int pfb = blk + PF;
        if (pfb < NBLK) {
#pragma unroll
            for (int t = 0; t < TB; ++t) {
                __builtin_amdgcn_global_load_lds(
                    (gptr_t)(xg + (ptrdiff_t)(pfb * TB + t) * BN),
                    (sptr_t)&lds[ws][t][0], 4, 0, 0);
            }
        }
        if (++rs == SLOTS) rs = 0;
        if (++ws == SLOTS) ws = 0;
    };

    // ramp: ops issued after block j's copies = 24/32/40, then 48 steady
    WAITVM(24); body(0);
    WAITVM(32); body(1);
    WAITVM(40); body(2);
    for (int blk = 3; blk < NBLK - PF; ++blk) {
        WAITVM(48);
        body(blk);
    }
    for (int blk = NBLK - PF; blk < NBLK; ++blk) {
        WAITVM(16);   // tail: stricter than needed (safe); no new prefetches
        body(blk);
    }
}

extern "C" void kernel_launch(void* const* d_in, const int* in_sizes, int n_in,
                              void* d_out, int out_size, void* d_ws, size_t ws_size,
                              hipStream_t stream) {
    const float* x        = (const float*)d_in[0];
    const float* beta_raw = (const float*)d_in[1];
    const float* p_raw    = (const float*)d_in[2];
    const float* b_raw    = (const float*)d_in[3];
    float* out            = (float*)d_out;

    dim3 grid(BN / 64);   // 512 workgroups of 1 wave
    dim3 block(64);
    snn_blocks_kernel<<<grid, block, 0, stream>>>(x, beta_raw, p_raw, b_raw, out);
}